// Round 10
// baseline (1166.641 us; speedup 1.0000x reference)
//
#include <hip/hip_runtime.h>
#include <hip/hip_bf16.h>
#include <math.h>

#define HCX 128   // H*C
#define EDX 64    // edge feature dim
#define KPAD 384  // unified GEMM K (layer 0 zero-pads first 128)

typedef short bf16x8 __attribute__((ext_vector_type(8)));
typedef float f32x4  __attribute__((ext_vector_type(4)));

__device__ __forceinline__ short f2bf(float v) {
    __hip_bfloat16 b = __float2bfloat16(v);
    return *reinterpret_cast<short*>(&b);
}
__device__ __forceinline__ float bf2f(short s) {
    __hip_bfloat16 b = *reinterpret_cast<__hip_bfloat16*>(&s);
    return __bfloat162float(b);
}
__device__ __forceinline__ void gload16(const short* g, short* l) {
    __builtin_amdgcn_global_load_lds((const __attribute__((address_space(1))) void*)g,
                                     (__attribute__((address_space(3))) void*)l, 16, 0, 0);
}
__device__ __forceinline__ float dot4(float4 a, float4 b) {
    return a.x * b.x + a.y * b.y + a.z * b.z + a.w * b.w;
}

// ---------------- CSR build ----------------
__global__ __launch_bounds__(256) void k_zero_deg(int* __restrict__ deg, int n) {
    int t = blockIdx.x * 256 + threadIdx.x;
    if (t < n) deg[t] = 0;
}

__global__ __launch_bounds__(256) void k_hist(const int* __restrict__ dst, int* __restrict__ deg, int nE) {
    int t = blockIdx.x * 256 + threadIdx.x;
    if (t < nE) atomicAdd(&deg[dst[t]], 1);
}

__global__ __launch_bounds__(1024) void k_scan(const int* __restrict__ deg, int* __restrict__ csr_off,
                                               int* __restrict__ cursor, int nN) {
    __shared__ int sums[1024];
    int t = threadIdx.x;
    int chunk = (nN + 1023) >> 10;
    int lo = min(t * chunk, nN), hi = min(lo + chunk, nN);
    int s = 0;
    for (int i = lo; i < hi; ++i) s += deg[i];
    sums[t] = s;
    __syncthreads();
    for (int off = 1; off < 1024; off <<= 1) {
        int v = (t >= off) ? sums[t - off] : 0;
        __syncthreads();
        sums[t] += v;
        __syncthreads();
    }
    int run = (t == 0) ? 0 : sums[t - 1];
    for (int i = lo; i < hi; ++i) {
        csr_off[i] = run; cursor[i] = run;
        run += deg[i];
    }
    if (t == 1023) csr_off[nN] = sums[1023];
}

__global__ __launch_bounds__(256) void k_scatter(const int* __restrict__ dst, const int* __restrict__ src,
                                                 int* __restrict__ cursor,
                                                 int* __restrict__ edge_sorted, int* __restrict__ src_sorted,
                                                 int* __restrict__ dst_sorted, int nE) {
    int t = blockIdx.x * 256 + threadIdx.x;
    if (t < nE) {
        int d = dst[t];
        int pos = atomicAdd(&cursor[d], 1);
        edge_sorted[pos] = t;
        src_sorted[pos]  = src[t];
        dst_sorted[pos]  = d;
    }
}

// ---------------- ea gather into CSR order (layer-invariant, done once) ----------------
// 16 threads per edge: coalesced 256B row read, fully sequential write.
__global__ __launch_bounds__(256) void k_gather_ea(const float* __restrict__ ea,
                                                   const int* __restrict__ edge_sorted,
                                                   float* __restrict__ ea_s, int nE)
{
    int t = blockIdx.x * 256 + threadIdx.x;
    int i = t >> 4, c = (t & 15) * 4;
    if (i < nE) {
        int eid = edge_sorted[i];
        *(float4*)(ea_s + (size_t)i * EDX + c) = *(const float4*)(ea + (size_t)eid * EDX + c);
    }
}

// ---------------- bf16 hi/lo conversions ----------------
__global__ __launch_bounds__(256) void k_cvt_h(const float* __restrict__ pH, int has_h,
                                               short* __restrict__ Ah, short* __restrict__ Al,
                                               int nN, int Mpad)
{
    int t = blockIdx.x * 256 + threadIdx.x;
    int row = t >> 5;
    if (row >= Mpad) return;
    int c0 = (t & 31) * 4;
    float4 v = make_float4(0.f, 0.f, 0.f, 0.f);
    if (has_h && row < nN) v = *(const float4*)(pH + (size_t)row * HCX + c0);
    short4 hs, ls;
    hs.x = f2bf(v.x); ls.x = f2bf(v.x - bf2f(hs.x));
    hs.y = f2bf(v.y); ls.y = f2bf(v.y - bf2f(hs.y));
    hs.z = f2bf(v.z); ls.z = f2bf(v.z - bf2f(hs.z));
    hs.w = f2bf(v.w); ls.w = f2bf(v.w - bf2f(hs.w));
    *(short4*)(Ah + (size_t)row * KPAD + c0) = hs;
    *(short4*)(Al + (size_t)row * KPAD + c0) = ls;
}

__global__ __launch_bounds__(256) void k_cvt_x(const float* __restrict__ x,
                                               short* __restrict__ Ah, short* __restrict__ Al,
                                               int nN, int Mpad)
{
    int t = blockIdx.x * 256 + threadIdx.x;
    int row = t >> 6;
    if (row >= Mpad) return;
    int c0 = (t & 63) * 4;
    float4 v = make_float4(0.f, 0.f, 0.f, 0.f);
    if (row < nN) v = *(const float4*)(x + (size_t)row * 256 + c0);
    short4 hs, ls;
    hs.x = f2bf(v.x); ls.x = f2bf(v.x - bf2f(hs.x));
    hs.y = f2bf(v.y); ls.y = f2bf(v.y - bf2f(hs.y));
    hs.z = f2bf(v.z); ls.z = f2bf(v.z - bf2f(hs.z));
    hs.w = f2bf(v.w); ls.w = f2bf(v.w - bf2f(hs.w));
    *(short4*)(Ah + (size_t)row * KPAD + 128 + c0) = hs;
    *(short4*)(Al + (size_t)row * KPAD + 128 + c0) = ls;
}

__global__ __launch_bounds__(384) void k_cvt_W(const float* __restrict__ Wq, const float* __restrict__ Wk,
                                               const float* __restrict__ Wv, const float* __restrict__ Ws,
                                               int koff, int dinW,
                                               short* __restrict__ Wth, short* __restrict__ Wtl)
{
    int col = blockIdx.x;
    int g = col >> 7, c = col & 127;
    const float* W = (g == 0) ? Wq : (g == 1) ? Wk : (g == 2) ? Wv : Ws;
    for (int k = threadIdx.x; k < KPAD; k += blockDim.x) {
        int kr = k - koff;
        float v = (kr >= 0 && kr < dinW) ? W[(size_t)kr * HCX + c] : 0.f;
        short h = f2bf(v);
        Wth[(size_t)col * KPAD + k] = h;
        Wtl[(size_t)col * KPAD + k] = f2bf(v - bf2f(h));
    }
}

// ---------------- MFMA GEMM: qkvs[g] = A @ Wt[g]^T + bias_g  (bf16x3) ----------------
__global__ __launch_bounds__(256) void k_gemm(
    const short* __restrict__ Ah, const short* __restrict__ Al,
    const short* __restrict__ Wth, const short* __restrict__ Wtl,
    const float* __restrict__ bq, const float* __restrict__ bk,
    const float* __restrict__ bv, const float* __restrict__ bs,
    float* __restrict__ qkvs, int nN)
{
    __shared__ short AsH[128 * 32];
    __shared__ short AsL[128 * 32];
    __shared__ short BsH[128 * 32];
    __shared__ short BsL[128 * 32];

    const int rowB = blockIdx.x * 128;
    const int g = blockIdx.y;
    const int colB = g * 128;
    const int tid = threadIdx.x;
    const int w = tid >> 6, l = tid & 63;

    f32x4 acc[4][4];
    #pragma unroll
    for (int i = 0; i < 4; ++i)
        #pragma unroll
        for (int j = 0; j < 4; ++j)
            acc[i][j] = (f32x4){0.f, 0.f, 0.f, 0.f};

    const int lrow4 = l >> 2;
    const int gch = (l & 3) ^ ((l >> 3) & 3);
    const int lr = l & 15, kg = l >> 4;

    for (int ks = 0; ks < KPAD / 32; ++ks) {
        const int k0 = ks * 32;
        #pragma unroll
        for (int jj = 0; jj < 2; ++jj) {
            int j = w + jj * 4;
            int rr = j * 16 + lrow4;
            size_t aoff = (size_t)(rowB + rr) * KPAD + k0 + gch * 8;
            size_t boff = (size_t)(colB + rr) * KPAD + k0 + gch * 8;
            gload16(Ah  + aoff, AsH + j * 512);
            gload16(Al  + aoff, AsL + j * 512);
            gload16(Wth + boff, BsH + j * 512);
            gload16(Wtl + boff, BsL + j * 512);
        }
        __syncthreads();

        bf16x8 ah[4], am[4], bh[4], bm[4];
        #pragma unroll
        for (int mi = 0; mi < 4; ++mi) {
            int r = (w >> 1) * 64 + mi * 16 + lr;
            int ch = kg ^ ((r >> 1) & 3);
            int off = r * 32 + ch * 8;
            ah[mi] = *(const bf16x8*)(AsH + off);
            am[mi] = *(const bf16x8*)(AsL + off);
        }
        #pragma unroll
        for (int ni = 0; ni < 4; ++ni) {
            int c = (w & 1) * 64 + ni * 16 + lr;
            int ch = kg ^ ((c >> 1) & 3);
            int off = c * 32 + ch * 8;
            bh[ni] = *(const bf16x8*)(BsH + off);
            bm[ni] = *(const bf16x8*)(BsL + off);
        }
        #pragma unroll
        for (int mi = 0; mi < 4; ++mi)
            #pragma unroll
            for (int ni = 0; ni < 4; ++ni) {
                acc[mi][ni] = __builtin_amdgcn_mfma_f32_16x16x32_bf16(ah[mi], bh[ni], acc[mi][ni], 0, 0, 0);
                acc[mi][ni] = __builtin_amdgcn_mfma_f32_16x16x32_bf16(ah[mi], bm[ni], acc[mi][ni], 0, 0, 0);
                acc[mi][ni] = __builtin_amdgcn_mfma_f32_16x16x32_bf16(am[mi], bh[ni], acc[mi][ni], 0, 0, 0);
            }
        __syncthreads();
    }

    const float* bias = (g == 0) ? bq : (g == 1) ? bk : (g == 2) ? bv : bs;
    float* outp = qkvs + (size_t)g * nN * HCX;
    const int lq = l >> 4;
    #pragma unroll
    for (int mi = 0; mi < 4; ++mi)
        #pragma unroll
        for (int ni = 0; ni < 4; ++ni) {
            int c = (w & 1) * 64 + ni * 16 + lr;
            float bb = bias[c];
            #pragma unroll
            for (int j = 0; j < 4; ++j) {
                int r = rowB + (w >> 1) * 64 + mi * 16 + lq * 4 + j;
                if (r < nN) outp[(size_t)r * HCX + c] = acc[mi][ni][j] + bb;
            }
        }
}

// ---------------- qWe[n,h,d] = sum_c q[n,h,c] * We[d, h*32+c] ----------------
__global__ __launch_bounds__(256) void k_qwe(const float* __restrict__ qpl,
                                             const float* __restrict__ We,
                                             float* __restrict__ qWe, int nN)
{
    __shared__ float Wes[64 * 128];
    __shared__ float qs[16][128];
    for (int i = threadIdx.x; i < 64 * 128; i += 256) {
        int d = i >> 7, c = i & 127;
        Wes[d * 128 + ((c + d) & 127)] = We[i];
    }
    int nb = blockIdx.x * 16;
    for (int i = threadIdx.x; i < 16 * 128; i += 256) {
        int r = i >> 7, c = i & 127;
        int row = nb + r;
        qs[r][c] = (row < nN) ? qpl[(size_t)row * HCX + c] : 0.f;
    }
    __syncthreads();
    int h = threadIdx.x >> 6, d = threadIdx.x & 63;
    const int base = h * 32;
    for (int r = 0; r < 16; ++r) {
        int row = nb + r;
        if (row >= nN) break;
        float s = 0.f;
        #pragma unroll
        for (int c = 0; c < 32; ++c)
            s += qs[r][base + c] * Wes[d * 128 + ((base + c + d) & 127)];
        qWe[(size_t)row * 256 + threadIdx.x] = s;
    }
}

// ---------------- edge-parallel score pass: one THREAD per edge, all 4 heads ----------------
// ea read once per edge (sequential when sorted); q/qWe broadcast across same-dst lanes.
__global__ __launch_bounds__(256) void k_alpha2(
    const float* __restrict__ qkvs, const float* __restrict__ qWe,
    const float* __restrict__ eaS,                 // sorted ea, or raw ea in fallback
    const int* __restrict__ eidx,                  // nullptr when eaS is sorted
    const int* __restrict__ src_sorted, const int* __restrict__ dst_sorted,
    float* __restrict__ expA, int nN, int nE)
{
    int i = blockIdx.x * 256 + threadIdx.x;
    if (i >= nE) return;
    int sn = src_sorted[i], dn = dst_sorted[i];
    int erow = eidx ? eidx[i] : i;

    const float* q = qkvs + (size_t)dn * HCX;
    const float* k = qkvs + (size_t)nN * HCX + (size_t)sn * HCX;
    float r[4];
    #pragma unroll
    for (int h = 0; h < 4; ++h) {
        float4 s4 = make_float4(0.f, 0.f, 0.f, 0.f);
        #pragma unroll
        for (int c = 0; c < 32; c += 4) {
            float4 qv = *(const float4*)(q + h * 32 + c);
            float4 kv = *(const float4*)(k + h * 32 + c);
            s4.x += qv.x * kv.x; s4.y += qv.y * kv.y;
            s4.z += qv.z * kv.z; s4.w += qv.w * kv.w;
        }
        r[h] = s4.x + s4.y + s4.z + s4.w;
    }

    const float* qw = qWe + (size_t)dn * 256;
    const float* ev = eaS + (size_t)erow * EDX;
    float th0 = 0.f, th1 = 0.f, th2 = 0.f, th3 = 0.f;
    #pragma unroll
    for (int d0 = 0; d0 < 64; d0 += 16) {          // ea chunk loaded once, used by all heads
        float4 a0 = *(const float4*)(ev + d0);
        float4 a1 = *(const float4*)(ev + d0 + 4);
        float4 a2 = *(const float4*)(ev + d0 + 8);
        float4 a3 = *(const float4*)(ev + d0 + 12);
        th0 += dot4(a0, *(const float4*)(qw +   0 + d0)) + dot4(a1, *(const float4*)(qw +   0 + d0 + 4))
             + dot4(a2, *(const float4*)(qw +   0 + d0 + 8)) + dot4(a3, *(const float4*)(qw +   0 + d0 + 12));
        th1 += dot4(a0, *(const float4*)(qw +  64 + d0)) + dot4(a1, *(const float4*)(qw +  64 + d0 + 4))
             + dot4(a2, *(const float4*)(qw +  64 + d0 + 8)) + dot4(a3, *(const float4*)(qw +  64 + d0 + 12));
        th2 += dot4(a0, *(const float4*)(qw + 128 + d0)) + dot4(a1, *(const float4*)(qw + 128 + d0 + 4))
             + dot4(a2, *(const float4*)(qw + 128 + d0 + 8)) + dot4(a3, *(const float4*)(qw + 128 + d0 + 12));
        th3 += dot4(a0, *(const float4*)(qw + 192 + d0)) + dot4(a1, *(const float4*)(qw + 192 + d0 + 4))
             + dot4(a2, *(const float4*)(qw + 192 + d0 + 8)) + dot4(a3, *(const float4*)(qw + 192 + d0 + 12));
    }

    const float scale = 0.17677669529663687f;   // 1/sqrt(32)
    // softmax is shift-invariant; scores are O(10), exp() cannot overflow fp32.
    float4 out;
    out.x = __expf((r[0] + th0) * scale);
    out.y = __expf((r[1] + th1) * scale);
    out.z = __expf((r[2] + th2) * scale);
    out.w = __expf((r[3] + th3) * scale);
    *(float4*)(expA + (size_t)i * 4) = out;
}

// ---------------- per-node aggregation (no shuffles, no exp) ----------------
// block 256 = 4 waves; wave wv handles node blockIdx*4+wv; lane owns channels l and 64+l
__global__ __launch_bounds__(256) void k_edge2(
    const float* __restrict__ qkvs, const float* __restrict__ expA,
    const float* __restrict__ eaS, const int* __restrict__ eidx,
    const float* __restrict__ We,
    const int* __restrict__ csr_off, const int* __restrict__ src_sorted,
    float* __restrict__ hout, int nN)
{
    __shared__ float wea_s[4][4][64];
    const int wv = threadIdx.x >> 6, l = threadIdx.x & 63;
    const int n = blockIdx.x * 4 + wv;
    const bool active = n < nN;
    int o0 = 0, o1 = 0;
    if (active) { o0 = csr_off[n]; o1 = csr_off[n + 1]; }

    const float* vpl = qkvs + 2 * (size_t)nN * HCX;
    const int hsel = l >> 5;

    float den0 = 0.f, den1 = 0.f, den2 = 0.f, den3 = 0.f;
    float w0 = 0.f, w1 = 0.f, w2 = 0.f, w3 = 0.f;
    float macc0 = 0.f, macc1 = 0.f;

    #pragma unroll 2
    for (int i = o0; i < o1; ++i) {
        float4 e4 = *(const float4*)(expA + (size_t)i * 4);   // uniform across wave
        int erow = eidx ? eidx[i] : i;
        int sn  = src_sorted[i];
        float eav = eaS[(size_t)erow * EDX + l];
        float vv0 = vpl[(size_t)sn * HCX + l];
        float vv1 = vpl[(size_t)sn * HCX + 64 + l];

        den0 += e4.x; den1 += e4.y; den2 += e4.z; den3 += e4.w;
        w0 += e4.x * eav; w1 += e4.y * eav; w2 += e4.z * eav; w3 += e4.w * eav;
        float eA = hsel ? e4.y : e4.x;
        float eB = hsel ? e4.w : e4.z;
        macc0 += eA * vv0;
        macc1 += eB * vv1;
    }

    wea_s[wv][0][l] = w0; wea_s[wv][1][l] = w1;
    wea_s[wv][2][l] = w2; wea_s[wv][3][l] = w3;
    __syncthreads();

    float acc1 = macc0, acc2 = macc1;
    const int h1 = hsel, h2 = 2 + hsel;
    #pragma unroll 8
    for (int d = 0; d < 64; ++d) {
        acc1 += wea_s[wv][h1][d] * We[d * HCX + l];
        acc2 += wea_s[wv][h2][d] * We[d * HCX + 64 + l];
    }
    if (active) {
        float d1 = (hsel ? den1 : den0) + 1e-16f;
        float d2 = (hsel ? den3 : den2) + 1e-16f;
        const float* spl = qkvs + 3 * (size_t)nN * HCX + (size_t)n * HCX;
        hout[(size_t)n * HCX + l]      = acc1 / d1 + spl[l];
        hout[(size_t)n * HCX + 64 + l] = acc2 / d2 + spl[64 + l];
    }
}

// ---------------- final: out = h @ Wout + bout ----------------
__global__ __launch_bounds__(256) void k_out(const float* __restrict__ h,
                                             const float* __restrict__ Wout,
                                             const float* __restrict__ bout,
                                             float* __restrict__ out, int nN)
{
    __shared__ float hs[8][128];
    int nb = blockIdx.x * 8;
    for (int i = threadIdx.x; i < 8 * 128; i += 256) {
        int r = i >> 7, c = i & 127;
        int row = nb + r;
        hs[r][c] = (row < nN) ? h[(size_t)row * 128 + c] : 0.f;
    }
    __syncthreads();
    int r = threadIdx.x >> 5, col = threadIdx.x & 31;
    int row = nb + r;
    if (row < nN) {
        float s = bout[col];
        #pragma unroll 16
        for (int c = 0; c < 128; ++c) s += hs[r][c] * Wout[c * 32 + col];
        out[(size_t)row * 32 + col] = s;
    }
}

// ---------------- host ----------------
static inline size_t align_up(size_t v, size_t a) { return (v + a - 1) & ~(a - 1); }

extern "C" void kernel_launch(void* const* d_in, const int* in_sizes, int n_in,
                              void* d_out, int out_size, void* d_ws, size_t ws_size,
                              hipStream_t stream)
{
    const float* x  = (const float*)d_in[0];
    const int*   ei = (const int*)d_in[1];
    const float* ea = (const float*)d_in[2];
    const int nN = in_sizes[0] / 256;
    const int nE = in_sizes[1] / 2;
    const int Mpad = (nN + 127) & ~127;
    const int* src = ei;
    const int* dst = ei + nE;

    char* p = (char*)d_ws;
    size_t off = 0;
    auto take = [&](size_t bytes) { void* r = p + off; off = align_up(off + bytes, 256); return r; };
    int* csr_off     = (int*)take((size_t)(nN + 1) * 4);
    int* cursor      = (int*)take((size_t)nN * 4);
    int* deg         = (int*)take((size_t)nN * 4);
    int* edge_sorted = (int*)take((size_t)nE * 4);
    int* src_sorted  = (int*)take((size_t)nE * 4);
    int* dst_sorted  = (int*)take((size_t)nE * 4);
    float* qkvs = (float*)take((size_t)4 * nN * HCX * 4);
    float* qWe  = (float*)take((size_t)nN * 256 * 4);
    float* expA = (float*)take((size_t)nE * 4 * 4);
    float* h0   = (float*)take((size_t)nN * HCX * 4);
    float* h1   = (float*)take((size_t)nN * HCX * 4);
    short* Ah   = (short*)take((size_t)Mpad * KPAD * 2);
    short* Al   = (short*)take((size_t)Mpad * KPAD * 2);
    short* Wth  = (short*)take((size_t)512 * KPAD * 2);
    short* Wtl  = (short*)take((size_t)512 * KPAD * 2);
    float* ea_s = (float*)take((size_t)nE * EDX * 4);   // appended last: layout above unchanged
    const bool use_sorted = (off <= ws_size);
    (void)n_in; (void)out_size;

    // CSR by dst (fixed across layers)
    k_zero_deg<<<(nN + 255) / 256, 256, 0, stream>>>(deg, nN);
    k_hist<<<(nE + 255) / 256, 256, 0, stream>>>(dst, deg, nE);
    k_scan<<<1, 1024, 0, stream>>>(deg, csr_off, cursor, nN);
    k_scatter<<<(nE + 255) / 256, 256, 0, stream>>>(dst, src, cursor,
                                                    edge_sorted, src_sorted, dst_sorted, nE);

    const float* eaS = use_sorted ? ea_s : ea;
    const int* eidx  = use_sorted ? nullptr : edge_sorted;
    if (use_sorted)
        k_gather_ea<<<(nE * 16 + 255) / 256, 256, 0, stream>>>(ea, edge_sorted, ea_s, nE);

    // x-part of A (cols 128..383), converted once
    k_cvt_x<<<(Mpad * 64 + 255) / 256, 256, 0, stream>>>(x, Ah, Al, nN, Mpad);

    auto layer = [&](const float* pH, int has_h, int base, float* hout) {
        const float* Wq = (const float*)d_in[base + 0];
        const float* bq = (const float*)d_in[base + 1];
        const float* Wk = (const float*)d_in[base + 2];
        const float* bk = (const float*)d_in[base + 3];
        const float* Wv = (const float*)d_in[base + 4];
        const float* bv = (const float*)d_in[base + 5];
        const float* We = (const float*)d_in[base + 6];
        const float* Ws = (const float*)d_in[base + 7];
        const float* bs = (const float*)d_in[base + 8];
        int koff = has_h ? 0 : 128;
        int dinW = has_h ? 384 : 256;
        k_cvt_h<<<(Mpad * 32 + 255) / 256, 256, 0, stream>>>(pH, has_h, Ah, Al, nN, Mpad);
        k_cvt_W<<<512, 384, 0, stream>>>(Wq, Wk, Wv, Ws, koff, dinW, Wth, Wtl);
        dim3 gg(Mpad / 128, 4);
        k_gemm<<<gg, 256, 0, stream>>>(Ah, Al, Wth, Wtl, bq, bk, bv, bs, qkvs, nN);
        k_qwe<<<(nN + 15) / 16, 256, 0, stream>>>(qkvs, We, qWe, nN);
        k_alpha2<<<(nE + 255) / 256, 256, 0, stream>>>(qkvs, qWe, eaS, eidx,
                                                       src_sorted, dst_sorted, expA, nN, nE);
        k_edge2<<<(nN + 3) / 4, 256, 0, stream>>>(qkvs, expA, eaS, eidx, We,
                                                  csr_off, src_sorted, hout, nN);
    };

    layer(nullptr, 0, 3,  h0);   // layer 0: input = x only (h-cols zero)
    layer(h0, 1,   12, h1);      // layer 1: input = [h0 | x]
    layer(h1, 1,   21, h0);      // layer 2: input = [h1 | x]

    k_out<<<(nN + 7) / 8, 256, 0, stream>>>(h0, (const float*)d_in[30], (const float*)d_in[31],
                                            (float*)d_out, nN);
}

// Round 12
// 1106.706 us; speedup vs baseline: 1.0542x; 1.0542x over previous
//
#include <hip/hip_runtime.h>
#include <hip/hip_bf16.h>
#include <math.h>

#define HCX 128   // H*C
#define EDX 64    // edge feature dim
#define KPAD 384  // unified GEMM K (layer 0 zero-pads first 128)

typedef short bf16x8 __attribute__((ext_vector_type(8)));
typedef float f32x4  __attribute__((ext_vector_type(4)));

__device__ __forceinline__ short f2bf(float v) {
    __hip_bfloat16 b = __float2bfloat16(v);
    return *reinterpret_cast<short*>(&b);
}
__device__ __forceinline__ float bf2f(short s) {
    unsigned int u = ((unsigned int)(unsigned short)s) << 16;
    return __uint_as_float(u);
}
__device__ __forceinline__ void gload16(const short* g, short* l) {
    __builtin_amdgcn_global_load_lds((const __attribute__((address_space(1))) void*)g,
                                     (__attribute__((address_space(3))) void*)l, 16, 0, 0);
}
__device__ __forceinline__ float dot4(float4 a, float4 b) {
    return a.x * b.x + a.y * b.y + a.z * b.z + a.w * b.w;
}

// ---------------- CSR build ----------------
__global__ __launch_bounds__(256) void k_zero_deg(int* __restrict__ deg, int n) {
    int t = blockIdx.x * 256 + threadIdx.x;
    if (t < n) deg[t] = 0;
}

__global__ __launch_bounds__(256) void k_hist(const int* __restrict__ dst, int* __restrict__ deg, int nE) {
    int t = blockIdx.x * 256 + threadIdx.x;
    if (t < nE) atomicAdd(&deg[dst[t]], 1);
}

__global__ __launch_bounds__(1024) void k_scan(const int* __restrict__ deg, int* __restrict__ csr_off,
                                               int* __restrict__ cursor, int nN) {
    __shared__ int sums[1024];
    int t = threadIdx.x;
    int chunk = (nN + 1023) >> 10;
    int lo = min(t * chunk, nN), hi = min(lo + chunk, nN);
    int s = 0;
    for (int i = lo; i < hi; ++i) s += deg[i];
    sums[t] = s;
    __syncthreads();
    for (int off = 1; off < 1024; off <<= 1) {
        int v = (t >= off) ? sums[t - off] : 0;
        __syncthreads();
        sums[t] += v;
        __syncthreads();
    }
    int run = (t == 0) ? 0 : sums[t - 1];
    for (int i = lo; i < hi; ++i) {
        csr_off[i] = run; cursor[i] = run;
        run += deg[i];
    }
    if (t == 1023) csr_off[nN] = sums[1023];
}

__global__ __launch_bounds__(256) void k_scatter(const int* __restrict__ dst, const int* __restrict__ src,
                                                 int* __restrict__ cursor,
                                                 int* __restrict__ edge_sorted, int* __restrict__ src_sorted,
                                                 int* __restrict__ dst_sorted, int nE) {
    int t = blockIdx.x * 256 + threadIdx.x;
    if (t < nE) {
        int d = dst[t];
        int pos = atomicAdd(&cursor[d], 1);
        edge_sorted[pos] = t;
        src_sorted[pos]  = src[t];
        dst_sorted[pos]  = d;
    }
}

// ---------------- ea gather into CSR order as bf16 (layer-invariant, once) ----------------
// 16 threads per edge: coalesced row read, sequential 8B writes.
__global__ __launch_bounds__(256) void k_gather_ea16(const float* __restrict__ ea,
                                                     const int* __restrict__ edge_sorted,
                                                     short* __restrict__ ea16, int nE)
{
    int t = blockIdx.x * 256 + threadIdx.x;
    int i = t >> 4, c = (t & 15) * 4;
    if (i < nE) {
        int eid = edge_sorted[i];
        float4 v = *(const float4*)(ea + (size_t)eid * EDX + c);
        short4 s;
        s.x = f2bf(v.x); s.y = f2bf(v.y); s.z = f2bf(v.z); s.w = f2bf(v.w);
        *(short4*)(ea16 + (size_t)i * EDX + c) = s;
    }
}

// ---------------- bf16 hi/lo conversions ----------------
__global__ __launch_bounds__(256) void k_cvt_h(const float* __restrict__ pH, int has_h,
                                               short* __restrict__ Ah, short* __restrict__ Al,
                                               int nN, int Mpad)
{
    int t = blockIdx.x * 256 + threadIdx.x;
    int row = t >> 5;
    if (row >= Mpad) return;
    int c0 = (t & 31) * 4;
    float4 v = make_float4(0.f, 0.f, 0.f, 0.f);
    if (has_h && row < nN) v = *(const float4*)(pH + (size_t)row * HCX + c0);
    short4 hs, ls;
    hs.x = f2bf(v.x); ls.x = f2bf(v.x - bf2f(hs.x));
    hs.y = f2bf(v.y); ls.y = f2bf(v.y - bf2f(hs.y));
    hs.z = f2bf(v.z); ls.z = f2bf(v.z - bf2f(hs.z));
    hs.w = f2bf(v.w); ls.w = f2bf(v.w - bf2f(hs.w));
    *(short4*)(Ah + (size_t)row * KPAD + c0) = hs;
    *(short4*)(Al + (size_t)row * KPAD + c0) = ls;
}

__global__ __launch_bounds__(256) void k_cvt_x(const float* __restrict__ x,
                                               short* __restrict__ Ah, short* __restrict__ Al,
                                               int nN, int Mpad)
{
    int t = blockIdx.x * 256 + threadIdx.x;
    int row = t >> 6;
    if (row >= Mpad) return;
    int c0 = (t & 63) * 4;
    float4 v = make_float4(0.f, 0.f, 0.f, 0.f);
    if (row < nN) v = *(const float4*)(x + (size_t)row * 256 + c0);
    short4 hs, ls;
    hs.x = f2bf(v.x); ls.x = f2bf(v.x - bf2f(hs.x));
    hs.y = f2bf(v.y); ls.y = f2bf(v.y - bf2f(hs.y));
    hs.z = f2bf(v.z); ls.z = f2bf(v.z - bf2f(hs.z));
    hs.w = f2bf(v.w); ls.w = f2bf(v.w - bf2f(hs.w));
    *(short4*)(Ah + (size_t)row * KPAD + 128 + c0) = hs;
    *(short4*)(Al + (size_t)row * KPAD + 128 + c0) = ls;
}

__global__ __launch_bounds__(384) void k_cvt_W(const float* __restrict__ Wq, const float* __restrict__ Wk,
                                               const float* __restrict__ Wv, const float* __restrict__ Ws,
                                               int koff, int dinW,
                                               short* __restrict__ Wth, short* __restrict__ Wtl)
{
    int col = blockIdx.x;
    int g = col >> 7, c = col & 127;
    const float* W = (g == 0) ? Wq : (g == 1) ? Wk : (g == 2) ? Wv : Ws;
    for (int k = threadIdx.x; k < KPAD; k += blockDim.x) {
        int kr = k - koff;
        float v = (kr >= 0 && kr < dinW) ? W[(size_t)kr * HCX + c] : 0.f;
        short h = f2bf(v);
        Wth[(size_t)col * KPAD + k] = h;
        Wtl[(size_t)col * KPAD + k] = f2bf(v - bf2f(h));
    }
}

// ---------------- MFMA GEMM: qkvs[g] = A @ Wt[g]^T + bias_g  (bf16x3) ----------------
__global__ __launch_bounds__(256) void k_gemm(
    const short* __restrict__ Ah, const short* __restrict__ Al,
    const short* __restrict__ Wth, const short* __restrict__ Wtl,
    const float* __restrict__ bq, const float* __restrict__ bk,
    const float* __restrict__ bv, const float* __restrict__ bs,
    float* __restrict__ qkvs, int nN)
{
    __shared__ short AsH[128 * 32];
    __shared__ short AsL[128 * 32];
    __shared__ short BsH[128 * 32];
    __shared__ short BsL[128 * 32];

    const int rowB = blockIdx.x * 128;
    const int g = blockIdx.y;
    const int colB = g * 128;
    const int tid = threadIdx.x;
    const int w = tid >> 6, l = tid & 63;

    f32x4 acc[4][4];
    #pragma unroll
    for (int i = 0; i < 4; ++i)
        #pragma unroll
        for (int j = 0; j < 4; ++j)
            acc[i][j] = (f32x4){0.f, 0.f, 0.f, 0.f};

    const int lrow4 = l >> 2;
    const int gch = (l & 3) ^ ((l >> 3) & 3);
    const int lr = l & 15, kg = l >> 4;

    for (int ks = 0; ks < KPAD / 32; ++ks) {
        const int k0 = ks * 32;
        #pragma unroll
        for (int jj = 0; jj < 2; ++jj) {
            int j = w + jj * 4;
            int rr = j * 16 + lrow4;
            size_t aoff = (size_t)(rowB + rr) * KPAD + k0 + gch * 8;
            size_t boff = (size_t)(colB + rr) * KPAD + k0 + gch * 8;
            gload16(Ah  + aoff, AsH + j * 512);
            gload16(Al  + aoff, AsL + j * 512);
            gload16(Wth + boff, BsH + j * 512);
            gload16(Wtl + boff, BsL + j * 512);
        }
        __syncthreads();

        bf16x8 ah[4], am[4], bh[4], bm[4];
        #pragma unroll
        for (int mi = 0; mi < 4; ++mi) {
            int r = (w >> 1) * 64 + mi * 16 + lr;
            int ch = kg ^ ((r >> 1) & 3);
            int off = r * 32 + ch * 8;
            ah[mi] = *(const bf16x8*)(AsH + off);
            am[mi] = *(const bf16x8*)(AsL + off);
        }
        #pragma unroll
        for (int ni = 0; ni < 4; ++ni) {
            int c = (w & 1) * 64 + ni * 16 + lr;
            int ch = kg ^ ((c >> 1) & 3);
            int off = c * 32 + ch * 8;
            bh[ni] = *(const bf16x8*)(BsH + off);
            bm[ni] = *(const bf16x8*)(BsL + off);
        }
        #pragma unroll
        for (int mi = 0; mi < 4; ++mi)
            #pragma unroll
            for (int ni = 0; ni < 4; ++ni) {
                acc[mi][ni] = __builtin_amdgcn_mfma_f32_16x16x32_bf16(ah[mi], bh[ni], acc[mi][ni], 0, 0, 0);
                acc[mi][ni] = __builtin_amdgcn_mfma_f32_16x16x32_bf16(ah[mi], bm[ni], acc[mi][ni], 0, 0, 0);
                acc[mi][ni] = __builtin_amdgcn_mfma_f32_16x16x32_bf16(am[mi], bh[ni], acc[mi][ni], 0, 0, 0);
            }
        __syncthreads();
    }

    const float* bias = (g == 0) ? bq : (g == 1) ? bk : (g == 2) ? bv : bs;
    float* outp = qkvs + (size_t)g * nN * HCX;
    const int lq = l >> 4;
    #pragma unroll
    for (int mi = 0; mi < 4; ++mi)
        #pragma unroll
        for (int ni = 0; ni < 4; ++ni) {
            int c = (w & 1) * 64 + ni * 16 + lr;
            float bb = bias[c];
            #pragma unroll
            for (int j = 0; j < 4; ++j) {
                int r = rowB + (w >> 1) * 64 + mi * 16 + lq * 4 + j;
                if (r < nN) outp[(size_t)r * HCX + c] = acc[mi][ni][j] + bb;
            }
        }
}

// ---------------- qWe[n,h,d] = sum_c q[n,h,c] * We[d, h*32+c] ----------------
__global__ __launch_bounds__(256) void k_qwe(const float* __restrict__ qpl,
                                             const float* __restrict__ We,
                                             float* __restrict__ qWe, int nN)
{
    __shared__ float Wes[64 * 128];
    __shared__ float qs[16][128];
    for (int i = threadIdx.x; i < 64 * 128; i += 256) {
        int d = i >> 7, c = i & 127;
        Wes[d * 128 + ((c + d) & 127)] = We[i];
    }
    int nb = blockIdx.x * 16;
    for (int i = threadIdx.x; i < 16 * 128; i += 256) {
        int r = i >> 7, c = i & 127;
        int row = nb + r;
        qs[r][c] = (row < nN) ? qpl[(size_t)row * HCX + c] : 0.f;
    }
    __syncthreads();
    int h = threadIdx.x >> 6, d = threadIdx.x & 63;
    const int base = h * 32;
    for (int r = 0; r < 16; ++r) {
        int row = nb + r;
        if (row >= nN) break;
        float s = 0.f;
        #pragma unroll
        for (int c = 0; c < 32; ++c)
            s += qs[r][base + c] * Wes[d * 128 + ((base + c + d) & 127)];
        qWe[(size_t)row * 256 + threadIdx.x] = s;
    }
}

// ---------------- edge-parallel score pass: 2 threads per edge (head pairs) ----------------
// ea loaded as bf16 (sorted) or fp32+indirection (fallback); q/qWe broadcast per dst group.
__global__ __launch_bounds__(256) void k_alpha3(
    const float* __restrict__ qkvs, const float* __restrict__ qWe,
    const short* __restrict__ ea16,               // bf16 CSR-sorted rows, or nullptr
    const float* __restrict__ eaF,                // raw fp32 ea (fallback)
    const int* __restrict__ eidx,                 // fallback indirection (nullptr when sorted)
    const int* __restrict__ src_sorted, const int* __restrict__ dst_sorted,
    float* __restrict__ expA, int nN, int nE)
{
    int t = blockIdx.x * 256 + threadIdx.x;
    int i = t >> 1, hp = t & 1;                   // head pair: heads 2hp, 2hp+1
    if (i >= nE) return;
    int sn = src_sorted[i], dn = dst_sorted[i];

    const float* q = qkvs + (size_t)dn * HCX + hp * 64;
    const float* k = qkvs + (size_t)nN * HCX + (size_t)sn * HCX + hp * 64;
    float r0 = 0.f, r1 = 0.f;
    #pragma unroll
    for (int c = 0; c < 32; c += 4) {
        r0 += dot4(*(const float4*)(q + c),      *(const float4*)(k + c));
        r1 += dot4(*(const float4*)(q + 32 + c), *(const float4*)(k + 32 + c));
    }

    const float* qw = qWe + (size_t)dn * 256 + hp * 128;
    float t0 = 0.f, t1 = 0.f;
    if (ea16) {
        const short* ev = ea16 + (size_t)i * EDX;
        #pragma unroll
        for (int d0 = 0; d0 < 64; d0 += 8) {
            bf16x8 a8 = *(const bf16x8*)(ev + d0);
            float4 qa = *(const float4*)(qw + d0);
            float4 qb = *(const float4*)(qw + d0 + 4);
            float4 qc = *(const float4*)(qw + 64 + d0);
            float4 qd = *(const float4*)(qw + 64 + d0 + 4);
            float a0 = bf2f(a8[0]), a1 = bf2f(a8[1]), a2 = bf2f(a8[2]), a3 = bf2f(a8[3]);
            float a4 = bf2f(a8[4]), a5 = bf2f(a8[5]), a6 = bf2f(a8[6]), a7 = bf2f(a8[7]);
            t0 += a0 * qa.x + a1 * qa.y + a2 * qa.z + a3 * qa.w
                + a4 * qb.x + a5 * qb.y + a6 * qb.z + a7 * qb.w;
            t1 += a0 * qc.x + a1 * qc.y + a2 * qc.z + a3 * qc.w
                + a4 * qd.x + a5 * qd.y + a6 * qd.z + a7 * qd.w;
        }
    } else {
        const float* ev = eaF + (size_t)eidx[i] * EDX;
        #pragma unroll
        for (int d0 = 0; d0 < 64; d0 += 4) {
            float4 av = *(const float4*)(ev + d0);
            t0 += dot4(av, *(const float4*)(qw + d0));
            t1 += dot4(av, *(const float4*)(qw + 64 + d0));
        }
    }

    const float scale = 0.17677669529663687f;   // 1/sqrt(32)
    // softmax is shift-invariant; scores are O(10), exp() cannot overflow fp32.
    float2 o;
    o.x = __expf((r0 + t0) * scale);
    o.y = __expf((r1 + t1) * scale);
    *(float2*)(expA + (size_t)i * 4 + hp * 2) = o;
}

// ---------------- per-node aggregation (no shuffles, no exp) ----------------
// block 256 = 4 waves; wave wv handles node blockIdx*4+wv; lane owns channels l and 64+l
__global__ __launch_bounds__(256) void k_edge2(
    const float* __restrict__ qkvs, const float* __restrict__ expA,
    const short* __restrict__ ea16, const float* __restrict__ eaF,
    const int* __restrict__ eidx,
    const float* __restrict__ We,
    const int* __restrict__ csr_off, const int* __restrict__ src_sorted,
    float* __restrict__ hout, int nN)
{
    __shared__ float wea_s[4][4][64];
    const int wv = threadIdx.x >> 6, l = threadIdx.x & 63;
    const int n = blockIdx.x * 4 + wv;
    const bool active = n < nN;
    int o0 = 0, o1 = 0;
    if (active) { o0 = csr_off[n]; o1 = csr_off[n + 1]; }

    const float* vpl = qkvs + 2 * (size_t)nN * HCX;
    const int hsel = l >> 5;

    float den0 = 0.f, den1 = 0.f, den2 = 0.f, den3 = 0.f;
    float w0 = 0.f, w1 = 0.f, w2 = 0.f, w3 = 0.f;
    float macc0 = 0.f, macc1 = 0.f;

#define EDGE_BODY(EAV_EXPR)                                          \
    _Pragma("unroll 2")                                              \
    for (int i = o0; i < o1; ++i) {                                  \
        float4 e4 = *(const float4*)(expA + (size_t)i * 4);          \
        int sn = src_sorted[i];                                      \
        float eav = (EAV_EXPR);                                      \
        float vv0 = vpl[(size_t)sn * HCX + l];                       \
        float vv1 = vpl[(size_t)sn * HCX + 64 + l];                  \
        den0 += e4.x; den1 += e4.y; den2 += e4.z; den3 += e4.w;      \
        w0 += e4.x * eav; w1 += e4.y * eav;                          \
        w2 += e4.z * eav; w3 += e4.w * eav;                          \
        float eA = hsel ? e4.y : e4.x;                               \
        float eB = hsel ? e4.w : e4.z;                               \
        macc0 += eA * vv0;                                           \
        macc1 += eB * vv1;                                           \
    }

    if (ea16) {
        EDGE_BODY(bf2f(ea16[(size_t)i * EDX + l]))
    } else {
        EDGE_BODY(eaF[(size_t)eidx[i] * EDX + l])
    }
#undef EDGE_BODY

    wea_s[wv][0][l] = w0; wea_s[wv][1][l] = w1;
    wea_s[wv][2][l] = w2; wea_s[wv][3][l] = w3;
    __syncthreads();

    float acc1 = macc0, acc2 = macc1;
    const int h1 = hsel, h2 = 2 + hsel;
    #pragma unroll 8
    for (int d = 0; d < 64; ++d) {
        acc1 += wea_s[wv][h1][d] * We[d * HCX + l];
        acc2 += wea_s[wv][h2][d] * We[d * HCX + 64 + l];
    }
    if (active) {
        float d1 = (hsel ? den1 : den0) + 1e-16f;
        float d2 = (hsel ? den3 : den2) + 1e-16f;
        const float* spl = qkvs + 3 * (size_t)nN * HCX + (size_t)n * HCX;
        hout[(size_t)n * HCX + l]      = acc1 / d1 + spl[l];
        hout[(size_t)n * HCX + 64 + l] = acc2 / d2 + spl[64 + l];
    }
}

// ---------------- final: out = h @ Wout + bout ----------------
__global__ __launch_bounds__(256) void k_out(const float* __restrict__ h,
                                             const float* __restrict__ Wout,
                                             const float* __restrict__ bout,
                                             float* __restrict__ out, int nN)
{
    __shared__ float hs[8][128];
    int nb = blockIdx.x * 8;
    for (int i = threadIdx.x; i < 8 * 128; i += 256) {
        int r = i >> 7, c = i & 127;
        int row = nb + r;
        hs[r][c] = (row < nN) ? h[(size_t)row * 128 + c] : 0.f;
    }
    __syncthreads();
    int r = threadIdx.x >> 5, col = threadIdx.x & 31;
    int row = nb + r;
    if (row < nN) {
        float s = bout[col];
        #pragma unroll 16
        for (int c = 0; c < 128; ++c) s += hs[r][c] * Wout[c * 32 + col];
        out[(size_t)row * 32 + col] = s;
    }
}

// ---------------- host ----------------
static inline size_t align_up(size_t v, size_t a) { return (v + a - 1) & ~(a - 1); }

extern "C" void kernel_launch(void* const* d_in, const int* in_sizes, int n_in,
                              void* d_out, int out_size, void* d_ws, size_t ws_size,
                              hipStream_t stream)
{
    const float* x  = (const float*)d_in[0];
    const int*   ei = (const int*)d_in[1];
    const float* ea = (const float*)d_in[2];
    const int nN = in_sizes[0] / 256;
    const int nE = in_sizes[1] / 2;
    const int Mpad = (nN + 127) & ~127;
    const int* src = ei;
    const int* dst = ei + nE;

    char* p = (char*)d_ws;
    size_t off = 0;
    auto take = [&](size_t bytes) { void* r = p + off; off = align_up(off + bytes, 256); return r; };
    int* csr_off     = (int*)take((size_t)(nN + 1) * 4);
    int* cursor      = (int*)take((size_t)nN * 4);
    int* deg         = (int*)take((size_t)nN * 4);
    int* edge_sorted = (int*)take((size_t)nE * 4);
    int* src_sorted  = (int*)take((size_t)nE * 4);
    int* dst_sorted  = (int*)take((size_t)nE * 4);
    float* qkvs = (float*)take((size_t)4 * nN * HCX * 4);
    float* qWe  = (float*)take((size_t)nN * 256 * 4);
    float* expA = (float*)take((size_t)nE * 4 * 4);
    float* h0   = (float*)take((size_t)nN * HCX * 4);
    float* h1   = (float*)take((size_t)nN * HCX * 4);
    short* Ah   = (short*)take((size_t)Mpad * KPAD * 2);
    short* Al   = (short*)take((size_t)Mpad * KPAD * 2);
    short* Wth  = (short*)take((size_t)512 * KPAD * 2);
    short* Wtl  = (short*)take((size_t)512 * KPAD * 2);
    short* ea16 = (short*)take((size_t)nE * EDX * 2);   // bf16 sorted ea (51 MB)
    const bool use_sorted = (off <= ws_size);
    (void)n_in; (void)out_size;

    // CSR by dst (fixed across layers)
    k_zero_deg<<<(nN + 255) / 256, 256, 0, stream>>>(deg, nN);
    k_hist<<<(nE + 255) / 256, 256, 0, stream>>>(dst, deg, nE);
    k_scan<<<1, 1024, 0, stream>>>(deg, csr_off, cursor, nN);
    k_scatter<<<(nE + 255) / 256, 256, 0, stream>>>(dst, src, cursor,
                                                    edge_sorted, src_sorted, dst_sorted, nE);

    short* ea16p    = use_sorted ? ea16 : nullptr;
    const int* eidx = use_sorted ? nullptr : edge_sorted;
    if (use_sorted)
        k_gather_ea16<<<(nE * 16 + 255) / 256, 256, 0, stream>>>(ea, edge_sorted, ea16, nE);

    // x-part of A (cols 128..383), converted once
    k_cvt_x<<<(Mpad * 64 + 255) / 256, 256, 0, stream>>>(x, Ah, Al, nN, Mpad);

    auto layer = [&](const float* pH, int has_h, int base, float* hout) {
        const float* Wq = (const float*)d_in[base + 0];
        const float* bq = (const float*)d_in[base + 1];
        const float* Wk = (const float*)d_in[base + 2];
        const float* bk = (const float*)d_in[base + 3];
        const float* Wv = (const float*)d_in[base + 4];
        const float* bv = (const float*)d_in[base + 5];
        const float* We = (const float*)d_in[base + 6];
        const float* Ws = (const float*)d_in[base + 7];
        const float* bs = (const float*)d_in[base + 8];
        int koff = has_h ? 0 : 128;
        int dinW = has_h ? 384 : 256;
        k_cvt_h<<<(Mpad * 32 + 255) / 256, 256, 0, stream>>>(pH, has_h, Ah, Al, nN, Mpad);
        k_cvt_W<<<512, 384, 0, stream>>>(Wq, Wk, Wv, Ws, koff, dinW, Wth, Wtl);
        dim3 gg(Mpad / 128, 4);
        k_gemm<<<gg, 256, 0, stream>>>(Ah, Al, Wth, Wtl, bq, bk, bv, bs, qkvs, nN);
        k_qwe<<<(nN + 15) / 16, 256, 0, stream>>>(qkvs, We, qWe, nN);
        k_alpha3<<<(nE * 2 + 255) / 256, 256, 0, stream>>>(qkvs, qWe, ea16p, ea, eidx,
                                                           src_sorted, dst_sorted, expA, nN, nE);
        k_edge2<<<(nN + 3) / 4, 256, 0, stream>>>(qkvs, expA, ea16p, ea, eidx, We,
                                                  csr_off, src_sorted, hout, nN);
    };

    layer(nullptr, 0, 3,  h0);   // layer 0: input = x only (h-cols zero)
    layer(h0, 1,   12, h1);      // layer 1: input = [h0 | x]
    layer(h1, 1,   21, h0);      // layer 2: input = [h1 | x]

    k_out<<<(nN + 7) / 8, 256, 0, stream>>>(h0, (const float*)d_in[30], (const float*)d_in[31],
                                            (float*)d_out, nN);
}